// Round 7
// baseline (195.476 us; speedup 1.0000x reference)
//
#include <hip/hip_runtime.h>
#include <stdint.h>

#define B_DIM 512
#define N_DIM 8192
#define D_DIM 1024
#define DA_DIM 512
#define S_DIM 8
#define DK_DIM 64
#define C_DIM 512   // S_DIM * DK_DIM

typedef short v8s __attribute__((ext_vector_type(8)));
typedef float v4f __attribute__((ext_vector_type(4)));

__device__ __forceinline__ unsigned int f2bf(float x) {
    union { float f; unsigned int u; } v; v.f = x;
    unsigned int u = v.u;
    return (u + 0x7fffu + ((u >> 16) & 1u)) >> 16;   // RNE f32 -> bf16
}

// ---------------- prep: all input conversions in one dispatch ----------------
__device__ __forceinline__ void cvt8(const float* __restrict__ src,
                                     unsigned short* __restrict__ dst, int t) {
    const float4* s4 = (const float4*)src;
    float4 a = s4[2 * t], b = s4[2 * t + 1];
    uint4 o;
    o.x = f2bf(a.x) | (f2bf(a.y) << 16);
    o.y = f2bf(a.z) | (f2bf(a.w) << 16);
    o.z = f2bf(b.x) | (f2bf(b.y) << 16);
    o.w = f2bf(b.z) | (f2bf(b.w) << 16);
    ((uint4*)dst)[t] = o;
}

__device__ __forceinline__ void w_transpose_tile(const float* __restrict__ w,
                                                 unsigned short* __restrict__ wt,
                                                 int a, int dt, int ddim,
                                                 unsigned short* T /* [64*68] */) {
    int t = threadIdx.x;
    int d0 = dt * 64;
    int kc4 = (t & 15) * 4;
    const float4* src = (const float4*)(w + ((size_t)a * ddim + d0) * DK_DIM);
    #pragma unroll
    for (int p = 0; p < 4; p++) {
        int dr = p * 16 + (t >> 4);
        float4 v = src[dr * 16 + (t & 15)];   // coalesced
        uint2 pk;
        pk.x = f2bf(v.x) | (f2bf(v.y) << 16);
        pk.y = f2bf(v.z) | (f2bf(v.w) << 16);
        *(uint2*)&T[dr * 68 + kc4] = pk;
    }
    __syncthreads();
    int c0 = a * 64;
    #pragma unroll
    for (int q = 0; q < 2; q++) {
        int k = q * 32 + (t >> 3);
        int ch = t & 7;
        unsigned short s[8];
        #pragma unroll
        for (int i = 0; i < 8; i++) s[i] = T[(ch * 8 + i) * 68 + k];
        uint4 o;
        o.x = (unsigned)s[0] | ((unsigned)s[1] << 16);
        o.y = (unsigned)s[2] | ((unsigned)s[3] << 16);
        o.z = (unsigned)s[4] | ((unsigned)s[5] << 16);
        o.w = (unsigned)s[6] | ((unsigned)s[7] << 16);
        *(uint4*)&wt[(size_t)(c0 + k) * ddim + d0 + ch * 8] = o;
    }
}

__global__ __launch_bounds__(256) void prep(const float* __restrict__ pool,
                                            const float* __restrict__ z,
                                            const float* __restrict__ W_Q,
                                            const float* __restrict__ W_K,
                                            unsigned short* __restrict__ poolb,
                                            unsigned short* __restrict__ zb,
                                            unsigned short* __restrict__ wqt,
                                            unsigned short* __restrict__ wtb) {
    __shared__ unsigned short T[64 * 68];
    int blk = blockIdx.x;
    if (blk < 4096) {
        cvt8(pool, poolb, blk * 256 + threadIdx.x);
    } else if (blk < 4224) {
        cvt8(z, zb, (blk - 4096) * 256 + threadIdx.x);
    } else if (blk < 4352) {
        int idx = blk - 4224;                      // W_K: 8 aspects x 16 d-tiles
        w_transpose_tile(W_K, wtb, idx >> 4, idx & 15, D_DIM, T);
    } else {
        int idx = blk - 4352;                      // W_Q: 8 aspects x 8 d-tiles
        w_transpose_tile(W_Q, wqt, idx >> 3, idx & 7, DA_DIM, T);
    }
}

// ---------------- hand-pipelined register-direct MFMA mainloop ----------------
// C[128x64] += A[128xK] * B[64xK]^T, both K-contiguous. 4 waves stacked in M:
// wave w computes rows [w*32, w*32+32) x all 64 cols -> acc[2][4].
// No LDS, no barriers. Rotating 4-slot fragment pipeline keeps ~18 loads in
// flight so the compiler emits fine-grained s_waitcnt vmcnt(N>0) per step.
template <int KITERS>
__device__ __forceinline__ void gemm_pipe(const unsigned short* __restrict__ A, int lda,
                                          const unsigned short* __restrict__ Bm, int ldb,
                                          int mbase, int nbase, v4f acc[2][4]) {
    constexpr int PF = 4;
    int tid = threadIdx.x;
    int wid = tid >> 6, lane = tid & 63;
    int quad = lane >> 4, l16 = lane & 15;
    const unsigned short* Ab = A + (size_t)(mbase + wid * 32 + l16) * lda + quad * 8;
    const unsigned short* Bb = Bm + (size_t)(nbase + l16) * ldb + quad * 8;

    v8s apf[PF][2], bpf[PF][4];
    #pragma unroll
    for (int s = 0; s < PF; s++) {
        #pragma unroll
        for (int mt = 0; mt < 2; mt++)
            apf[s][mt] = *(const v8s*)(Ab + (size_t)mt * 16 * lda + s * 32);
        #pragma unroll
        for (int nt = 0; nt < 4; nt++)
            bpf[s][nt] = *(const v8s*)(Bb + (size_t)nt * 16 * ldb + s * 32);
    }
    #pragma unroll
    for (int kk = 0; kk < KITERS; kk++) {
        const int slot = kk % PF;
        v8s a0 = apf[slot][0], a1 = apf[slot][1];
        v8s b0 = bpf[slot][0], b1 = bpf[slot][1];
        v8s b2 = bpf[slot][2], b3 = bpf[slot][3];
        if (kk + PF < KITERS) {
            #pragma unroll
            for (int mt = 0; mt < 2; mt++)
                apf[slot][mt] = *(const v8s*)(Ab + (size_t)mt * 16 * lda + (kk + PF) * 32);
            #pragma unroll
            for (int nt = 0; nt < 4; nt++)
                bpf[slot][nt] = *(const v8s*)(Bb + (size_t)nt * 16 * ldb + (kk + PF) * 32);
        }
        acc[0][0] = __builtin_amdgcn_mfma_f32_16x16x32_bf16(a0, b0, acc[0][0], 0, 0, 0);
        acc[0][1] = __builtin_amdgcn_mfma_f32_16x16x32_bf16(a0, b1, acc[0][1], 0, 0, 0);
        acc[0][2] = __builtin_amdgcn_mfma_f32_16x16x32_bf16(a0, b2, acc[0][2], 0, 0, 0);
        acc[0][3] = __builtin_amdgcn_mfma_f32_16x16x32_bf16(a0, b3, acc[0][3], 0, 0, 0);
        acc[1][0] = __builtin_amdgcn_mfma_f32_16x16x32_bf16(a1, b0, acc[1][0], 0, 0, 0);
        acc[1][1] = __builtin_amdgcn_mfma_f32_16x16x32_bf16(a1, b1, acc[1][1], 0, 0, 0);
        acc[1][2] = __builtin_amdgcn_mfma_f32_16x16x32_bf16(a1, b2, acc[1][2], 0, 0, 0);
        acc[1][3] = __builtin_amdgcn_mfma_f32_16x16x32_bf16(a1, b3, acc[1][3], 0, 0, 0);
    }
}

// ---------------- fused keys-GEMM (+norm) and queries-GEMM (+norm+weight) ----------------
// blocks [0,512): keys. n-tile = blk&7 (64 cols), m-tile = blk>>3 (128 rows).
// blocks [512,544): queries. q = blk-512: n-tile = q&7, m-tile = q>>3.
__global__ __launch_bounds__(256, 2) void fused_gemms(const unsigned short* __restrict__ poolb,
                                                      const unsigned short* __restrict__ wtb,
                                                      const unsigned short* __restrict__ zb,
                                                      const unsigned short* __restrict__ wqt,
                                                      const float* __restrict__ logits,
                                                      float* __restrict__ keys_out,
                                                      unsigned short* __restrict__ kb,
                                                      unsigned short* __restrict__ qwb) {
    v4f acc[2][4];
    #pragma unroll
    for (int mt = 0; mt < 2; mt++)
        #pragma unroll
        for (int nt = 0; nt < 4; nt++) acc[mt][nt] = (v4f)(0.f);

    int blk = blockIdx.x;
    bool is_q = blk >= 512;
    int mbase, nbase;
    if (is_q) {
        int q = blk - 512;
        mbase = (q >> 3) * 128; nbase = (q & 7) * 64;
        gemm_pipe<DA_DIM / 32>(zb, DA_DIM, wqt, DA_DIM, mbase, nbase, acc);
    } else {
        mbase = (blk >> 3) * 128; nbase = (blk & 7) * 64;
        gemm_pipe<D_DIM / 32>(poolb, D_DIM, wtb, D_DIM, mbase, nbase, acc);
    }

    int tid = threadIdx.x, wid = tid >> 6, lane = tid & 63;
    int quad = lane >> 4, l16 = lane & 15;

    if (is_q) {
        float l[8]; float mx = -1e30f;
        #pragma unroll
        for (int i = 0; i < 8; i++) { l[i] = logits[i]; mx = fmaxf(mx, l[i]); }
        float se = 0.f;
        #pragma unroll
        for (int i = 0; i < 8; i++) { l[i] = __expf(l[i] - mx); se += l[i]; }
        float wa = l[nbase >> 6] / se;             // tile spans exactly one aspect

        #pragma unroll
        for (int mt = 0; mt < 2; mt++)
            #pragma unroll
            for (int r = 0; r < 4; r++) {
                float ss = 0.f;
                #pragma unroll
                for (int nt = 0; nt < 4; nt++) ss += acc[mt][nt][r] * acc[mt][nt][r];
                ss += __shfl_xor(ss, 1, 64);
                ss += __shfl_xor(ss, 2, 64);
                ss += __shfl_xor(ss, 4, 64);
                ss += __shfl_xor(ss, 8, 64);
                float sc = wa / (sqrtf(ss) + 1e-8f);
                int row = mbase + wid * 32 + mt * 16 + quad * 4 + r;
                #pragma unroll
                for (int nt = 0; nt < 4; nt++) {
                    int col = nbase + nt * 16 + l16;
                    qwb[(size_t)row * C_DIM + col] =
                        (unsigned short)f2bf(acc[mt][nt][r] * sc);
                }
            }
    } else {
        #pragma unroll
        for (int mt = 0; mt < 2; mt++)
            #pragma unroll
            for (int r = 0; r < 4; r++) {
                float ss = 0.f;
                #pragma unroll
                for (int nt = 0; nt < 4; nt++) ss += acc[mt][nt][r] * acc[mt][nt][r];
                ss += __shfl_xor(ss, 1, 64);
                ss += __shfl_xor(ss, 2, 64);
                ss += __shfl_xor(ss, 4, 64);
                ss += __shfl_xor(ss, 8, 64);
                float sc = 1.0f / (sqrtf(ss) + 1e-8f);
                int row = mbase + wid * 32 + mt * 16 + quad * 4 + r;
                #pragma unroll
                for (int nt = 0; nt < 4; nt++) {
                    int col = nbase + nt * 16 + l16;
                    float s = acc[mt][nt][r];
                    keys_out[(size_t)row * C_DIM + col] = s;
                    kb[(size_t)row * C_DIM + col] = (unsigned short)f2bf(s * sc);
                }
            }
    }
}

// ---------------- scores = Qw * K^T + epilogue partial row-sums ----------------
// grid (128, 4): x = n-tile (64 cols of N), y = m-tile (128 rows of B).
__global__ __launch_bounds__(256, 2) void scores_gemm(const unsigned short* __restrict__ qwb,
                                                      const unsigned short* __restrict__ kb,
                                                      float* __restrict__ scores_out,
                                                      float* __restrict__ partials,
                                                      const float* __restrict__ lam_p,
                                                      const float* __restrict__ tau_p,
                                                      const float* __restrict__ temp_p) {
    __shared__ float rowpart[128];
    v4f acc[2][4];
    #pragma unroll
    for (int mt = 0; mt < 2; mt++)
        #pragma unroll
        for (int nt = 0; nt < 4; nt++) acc[mt][nt] = (v4f)(0.f);

    int mbase = blockIdx.y * 128, nbase = blockIdx.x * 64;
    gemm_pipe<C_DIM / 32>(qwb, C_DIM, kb, C_DIM, mbase, nbase, acc);

    int tid = threadIdx.x, wid = tid >> 6, lane = tid & 63;
    int quad = lane >> 4, l16 = lane & 15;

    float lam = lam_p[0], tau = tau_p[0], invT = 1.0f / temp_p[0];

    #pragma unroll
    for (int mt = 0; mt < 2; mt++)
        #pragma unroll
        for (int r = 0; r < 4; r++) {
            float rs = 0.f;
            int row = mbase + wid * 32 + mt * 16 + quad * 4 + r;
            #pragma unroll
            for (int nt = 0; nt < 4; nt++) {
                float s = acc[mt][nt][r];
                int col = nbase + nt * 16 + l16;
                scores_out[(size_t)row * N_DIM + col] = s;
                float g = 1.0f / (1.0f + __expf(-lam * (s - tau)));
                rs += g * __expf(s * invT);
            }
            rs += __shfl_xor(rs, 1, 64);
            rs += __shfl_xor(rs, 2, 64);
            rs += __shfl_xor(rs, 4, 64);
            rs += __shfl_xor(rs, 8, 64);
            if (l16 == 0)
                rowpart[wid * 32 + mt * 16 + quad * 4 + r] = rs;
        }
    __syncthreads();
    if (tid < 128)
        partials[(size_t)blockIdx.x * B_DIM + mbase + tid] = rowpart[tid];
}

// ---------------- alpha = g*exp(s/T) / rowsum (128 partials reduced in-kernel) ----------------
__global__ __launch_bounds__(256) void alpha_kernel(const float* __restrict__ scores,
                                                    const float* __restrict__ partials,
                                                    float* __restrict__ alpha,
                                                    const float* __restrict__ lam_p,
                                                    const float* __restrict__ tau_p,
                                                    const float* __restrict__ temp_p) {
    __shared__ float red[128];
    __shared__ float s_inv;
    int b = blockIdx.x;                       // one row per block, 512 blocks
    int tid = threadIdx.x;
    if (tid < 128) red[tid] = partials[(size_t)tid * B_DIM + b];
    __syncthreads();
    if (tid < 64) {
        float v = red[tid] + red[tid + 64];
        v += __shfl_xor(v, 1, 64);
        v += __shfl_xor(v, 2, 64);
        v += __shfl_xor(v, 4, 64);
        v += __shfl_xor(v, 8, 64);
        v += __shfl_xor(v, 16, 64);
        v += __shfl_xor(v, 32, 64);
        if (tid == 0) s_inv = 1.0f / (v + 1e-8f);
    }
    __syncthreads();
    float inv = s_inv;
    float lam = lam_p[0], tau = tau_p[0], invT = 1.0f / temp_p[0];
    const float4* srow = (const float4*)(scores + (size_t)b * N_DIM);
    float4* arow = (float4*)(alpha + (size_t)b * N_DIM);
    #pragma unroll
    for (int i = 0; i < 8; i++) {
        int idx = tid + i * 256;              // 0..2047 float4
        float4 s4 = srow[idx];
        float4 o;
        o.x = (1.0f / (1.0f + __expf(-lam * (s4.x - tau)))) * __expf(s4.x * invT) * inv;
        o.y = (1.0f / (1.0f + __expf(-lam * (s4.y - tau)))) * __expf(s4.y * invT) * inv;
        o.z = (1.0f / (1.0f + __expf(-lam * (s4.z - tau)))) * __expf(s4.z * invT) * inv;
        o.w = (1.0f / (1.0f + __expf(-lam * (s4.w - tau)))) * __expf(s4.w * invT) * inv;
        arow[idx] = o;
    }
}

extern "C" void kernel_launch(void* const* d_in, const int* in_sizes, int n_in,
                              void* d_out, int out_size, void* d_ws, size_t ws_size,
                              hipStream_t stream) {
    const float* z      = (const float*)d_in[0];
    const float* pool   = (const float*)d_in[1];
    const float* W_Q    = (const float*)d_in[2];
    const float* W_K    = (const float*)d_in[3];
    const float* logits = (const float*)d_in[4];
    const float* tau    = (const float*)d_in[5];
    const float* lam    = (const float*)d_in[6];
    const float* temp   = (const float*)d_in[7];

    float* alpha  = (float*)d_out;
    float* scores = alpha + (size_t)B_DIM * N_DIM;
    float* keys   = scores + (size_t)B_DIM * N_DIM;

    char* ws = (char*)d_ws;
    unsigned short* poolb = (unsigned short*)(ws);             // 16,777,216 B
    unsigned short* kb    = (unsigned short*)(ws + 16777216);  //  8,388,608 B
    unsigned short* wtb   = (unsigned short*)(ws + 25165824);  //  1,048,576 B
    unsigned short* wqt   = (unsigned short*)(ws + 26214400);  //    524,288 B
    unsigned short* zb    = (unsigned short*)(ws + 26738688);  //    524,288 B
    unsigned short* qwb   = (unsigned short*)(ws + 27262976);  //    524,288 B
    float* partials       = (float*)(ws + 27787264);           //    262,144 B (128 x 512)

    prep<<<dim3(4416), dim3(256), 0, stream>>>(pool, z, W_Q, W_K,
                                               poolb, zb, wqt, wtb);
    fused_gemms<<<dim3(544), dim3(256), 0, stream>>>(poolb, wtb, zb, wqt, logits,
                                                     keys, kb, qwb);
    scores_gemm<<<dim3(128, 4), dim3(256), 0, stream>>>(qwb, kb, scores, partials,
                                                        lam, tau, temp);
    alpha_kernel<<<dim3(512), dim3(256), 0, stream>>>(scores, partials, alpha,
                                                      lam, tau, temp);
}

// Round 8
// 138.225 us; speedup vs baseline: 1.4142x; 1.4142x over previous
//
#include <hip/hip_runtime.h>
#include <stdint.h>

#define B_DIM 512
#define N_DIM 8192
#define D_DIM 1024
#define DA_DIM 512
#define S_DIM 8
#define DK_DIM 64
#define C_DIM 512   // S_DIM * DK_DIM

typedef short v8s __attribute__((ext_vector_type(8)));
typedef float v4f __attribute__((ext_vector_type(4)));

__device__ __forceinline__ unsigned int f2bf(float x) {
    union { float f; unsigned int u; } v; v.f = x;
    unsigned int u = v.u;
    return (u + 0x7fffu + ((u >> 16) & 1u)) >> 16;   // RNE f32 -> bf16
}

// async 16B global -> LDS (per-lane global gather; LDS dst = wave base + lane*16)
__device__ __forceinline__ void gld16(const unsigned short* g, unsigned short* l) {
    __builtin_amdgcn_global_load_lds(
        (const __attribute__((address_space(1))) unsigned int*)g,
        (__attribute__((address_space(3))) unsigned int*)l,
        16, 0, 0);
}

// ---------------- prep: all input conversions in one dispatch ----------------
__device__ __forceinline__ void cvt8(const float* __restrict__ src,
                                     unsigned short* __restrict__ dst, int t) {
    const float4* s4 = (const float4*)src;
    float4 a = s4[2 * t], b = s4[2 * t + 1];
    uint4 o;
    o.x = f2bf(a.x) | (f2bf(a.y) << 16);
    o.y = f2bf(a.z) | (f2bf(a.w) << 16);
    o.z = f2bf(b.x) | (f2bf(b.y) << 16);
    o.w = f2bf(b.z) | (f2bf(b.w) << 16);
    ((uint4*)dst)[t] = o;
}

__device__ __forceinline__ void w_transpose_tile(const float* __restrict__ w,
                                                 unsigned short* __restrict__ wt,
                                                 int a, int dt, int ddim,
                                                 unsigned short* T /* [64*68] */) {
    int t = threadIdx.x;
    int d0 = dt * 64;
    int kc4 = (t & 15) * 4;
    const float4* src = (const float4*)(w + ((size_t)a * ddim + d0) * DK_DIM);
    #pragma unroll
    for (int p = 0; p < 4; p++) {
        int dr = p * 16 + (t >> 4);
        float4 v = src[dr * 16 + (t & 15)];   // coalesced
        uint2 pk;
        pk.x = f2bf(v.x) | (f2bf(v.y) << 16);
        pk.y = f2bf(v.z) | (f2bf(v.w) << 16);
        *(uint2*)&T[dr * 68 + kc4] = pk;
    }
    __syncthreads();
    int c0 = a * 64;
    #pragma unroll
    for (int q = 0; q < 2; q++) {
        int k = q * 32 + (t >> 3);
        int ch = t & 7;
        unsigned short s[8];
        #pragma unroll
        for (int i = 0; i < 8; i++) s[i] = T[(ch * 8 + i) * 68 + k];
        uint4 o;
        o.x = (unsigned)s[0] | ((unsigned)s[1] << 16);
        o.y = (unsigned)s[2] | ((unsigned)s[3] << 16);
        o.z = (unsigned)s[4] | ((unsigned)s[5] << 16);
        o.w = (unsigned)s[6] | ((unsigned)s[7] << 16);
        *(uint4*)&wt[(size_t)(c0 + k) * ddim + d0 + ch * 8] = o;
    }
}

__global__ __launch_bounds__(256) void prep(const float* __restrict__ pool,
                                            const float* __restrict__ z,
                                            const float* __restrict__ W_Q,
                                            const float* __restrict__ W_K,
                                            unsigned short* __restrict__ poolb,
                                            unsigned short* __restrict__ zb,
                                            unsigned short* __restrict__ wqt,
                                            unsigned short* __restrict__ wtb) {
    __shared__ unsigned short T[64 * 68];
    int blk = blockIdx.x;
    if (blk < 4096) {
        cvt8(pool, poolb, blk * 256 + threadIdx.x);
    } else if (blk < 4224) {
        cvt8(z, zb, (blk - 4096) * 256 + threadIdx.x);
    } else if (blk < 4352) {
        int idx = blk - 4224;                      // W_K: 8 aspects x 16 d-tiles
        w_transpose_tile(W_K, wtb, idx >> 4, idx & 15, D_DIM, T);
    } else {
        int idx = blk - 4352;                      // W_Q: 8 aspects x 8 d-tiles
        w_transpose_tile(W_Q, wqt, idx >> 3, idx & 7, DA_DIM, T);
    }
}

// ---------------- MFMA mainloop: 128(m) x 64(n) tile, BK=64, dbuf LDS ----------------
// 4 waves stacked in M: wave w computes rows [w*32, w*32+32) x 64 cols -> acc[2][4].
// BK=64 staged as two BK=32 sub-chunks (each [rows][32 shorts], m97 layout).
// As[p][c]: 128x32 shorts (8 KB); Bs[p][c]: 64x32 shorts (4 KB). Total 48 KB.
__device__ __forceinline__ void gemm_mainloop(const unsigned short* __restrict__ A, int lda,
                                              const unsigned short* __restrict__ Bm, int ldb,
                                              int mbase, int nbase, int kiters64,
                                              unsigned short (*As)[2][4096],
                                              unsigned short (*Bs)[2][2048],
                                              v4f acc[2][4]) {
    int tid = threadIdx.x;
    int wid = tid >> 6, lane = tid & 63;
    int quad = lane >> 4, l16 = lane & 15;
    int srow = lane >> 2;            // 0..15 within a 16-row granule
    int scol = (lane & 3) * 8;       // shorts (16B granules), 4 lanes cover 64 shorts

    auto stage = [&](int kk, int p) {
        int k0 = kk * 64;
        #pragma unroll
        for (int j = 0; j < 6; j++) {
            int i = wid * 6 + j;                   // wave-uniform, 0..23
            if (i < 16) {                          // A: 2 halves x 8 granules
                int c = i >> 3, g = i & 7;
                int row = g * 16 + srow;
                gld16(&A[(size_t)(mbase + row) * lda + k0 + c * 32 + scol],
                      &As[p][c][g * 512]);
            } else {                               // B: 2 halves x 4 granules
                int i2 = i - 16;
                int c = i2 >> 2, g = i2 & 3;
                int row = g * 16 + srow;
                gld16(&Bm[(size_t)(nbase + row) * ldb + k0 + c * 32 + scol],
                      &Bs[p][c][g * 512]);
            }
        }
    };

    stage(0, 0);
    for (int kk = 0; kk < kiters64; kk++) {
        __syncthreads();                           // drains stage(kk) (vmcnt 0)
        if (kk + 1 < kiters64) stage(kk + 1, (kk + 1) & 1);  // overlaps compute below
        int p = kk & 1;
        #pragma unroll
        for (int c = 0; c < 2; c++) {
            v8s af[2], bf[4];
            #pragma unroll
            for (int mt = 0; mt < 2; mt++)
                af[mt] = *(const v8s*)&As[p][c][(wid * 32 + mt * 16 + l16) * 32 + quad * 8];
            #pragma unroll
            for (int nt = 0; nt < 4; nt++)
                bf[nt] = *(const v8s*)&Bs[p][c][(nt * 16 + l16) * 32 + quad * 8];
            #pragma unroll
            for (int mt = 0; mt < 2; mt++)
                #pragma unroll
                for (int nt = 0; nt < 4; nt++)
                    acc[mt][nt] = __builtin_amdgcn_mfma_f32_16x16x32_bf16(
                        af[mt], bf[nt], acc[mt][nt], 0, 0, 0);
        }
    }
}

// ---------------- fused keys-GEMM (+norm) and queries-GEMM (+norm+weight) ----------------
// keys blocks [0,512): m-tile = blk&63, n-tile = blk>>6  (same-A blocks share XCD:
//   blk for fixed m differs by 64 across n, 64%8==0 -> same XCD L2 caches the A slab)
// queries blocks [512,544): q = blk-512: m-tile = q&3, n-tile = q>>2.
__global__ __launch_bounds__(256, 2) void fused_gemms(const unsigned short* __restrict__ poolb,
                                                      const unsigned short* __restrict__ wtb,
                                                      const unsigned short* __restrict__ zb,
                                                      const unsigned short* __restrict__ wqt,
                                                      const float* __restrict__ logits,
                                                      float* __restrict__ keys_out,
                                                      unsigned short* __restrict__ kb,
                                                      unsigned short* __restrict__ qwb) {
    __shared__ unsigned short As[2][2][4096];
    __shared__ unsigned short Bs[2][2][2048];
    v4f acc[2][4];
    #pragma unroll
    for (int mt = 0; mt < 2; mt++)
        #pragma unroll
        for (int nt = 0; nt < 4; nt++) acc[mt][nt] = (v4f)(0.f);

    int blk = blockIdx.x;
    bool is_q = blk >= 512;
    int mbase, nbase;
    if (is_q) {
        int q = blk - 512;
        mbase = (q & 3) * 128; nbase = (q >> 2) * 64;
        gemm_mainloop(zb, DA_DIM, wqt, DA_DIM, mbase, nbase, DA_DIM / 64, As, Bs, acc);
    } else {
        mbase = (blk & 63) * 128; nbase = (blk >> 6) * 64;
        gemm_mainloop(poolb, D_DIM, wtb, D_DIM, mbase, nbase, D_DIM / 64, As, Bs, acc);
    }

    int tid = threadIdx.x, wid = tid >> 6, lane = tid & 63;
    int quad = lane >> 4, l16 = lane & 15;

    if (is_q) {
        float l[8]; float mx = -1e30f;
        #pragma unroll
        for (int i = 0; i < 8; i++) { l[i] = logits[i]; mx = fmaxf(mx, l[i]); }
        float se = 0.f;
        #pragma unroll
        for (int i = 0; i < 8; i++) { l[i] = __expf(l[i] - mx); se += l[i]; }
        float wa = l[nbase >> 6] / se;             // tile spans exactly one aspect

        #pragma unroll
        for (int mt = 0; mt < 2; mt++)
            #pragma unroll
            for (int r = 0; r < 4; r++) {
                float ss = 0.f;
                #pragma unroll
                for (int nt = 0; nt < 4; nt++) ss += acc[mt][nt][r] * acc[mt][nt][r];
                ss += __shfl_xor(ss, 1, 64);
                ss += __shfl_xor(ss, 2, 64);
                ss += __shfl_xor(ss, 4, 64);
                ss += __shfl_xor(ss, 8, 64);
                float sc = wa / (sqrtf(ss) + 1e-8f);
                int row = mbase + wid * 32 + mt * 16 + quad * 4 + r;
                #pragma unroll
                for (int nt = 0; nt < 4; nt++) {
                    int col = nbase + nt * 16 + l16;
                    qwb[(size_t)row * C_DIM + col] =
                        (unsigned short)f2bf(acc[mt][nt][r] * sc);
                }
            }
    } else {
        #pragma unroll
        for (int mt = 0; mt < 2; mt++)
            #pragma unroll
            for (int r = 0; r < 4; r++) {
                float ss = 0.f;
                #pragma unroll
                for (int nt = 0; nt < 4; nt++) ss += acc[mt][nt][r] * acc[mt][nt][r];
                ss += __shfl_xor(ss, 1, 64);
                ss += __shfl_xor(ss, 2, 64);
                ss += __shfl_xor(ss, 4, 64);
                ss += __shfl_xor(ss, 8, 64);
                float sc = 1.0f / (sqrtf(ss) + 1e-8f);
                int row = mbase + wid * 32 + mt * 16 + quad * 4 + r;
                #pragma unroll
                for (int nt = 0; nt < 4; nt++) {
                    int col = nbase + nt * 16 + l16;
                    float s = acc[mt][nt][r];
                    keys_out[(size_t)row * C_DIM + col] = s;
                    kb[(size_t)row * C_DIM + col] = (unsigned short)f2bf(s * sc);
                }
            }
    }
}

// ---------------- scores = Qw * K^T + epilogue partial row-sums ----------------
// grid (128, 4): x = n-tile (64 cols of N), y = m-tile (128 rows of B).
// Same-n blocks (sharing the kb slab) have linear id differing by 128 (==0 mod 8)
// -> same XCD L2.
__global__ __launch_bounds__(256, 2) void scores_gemm(const unsigned short* __restrict__ qwb,
                                                      const unsigned short* __restrict__ kb,
                                                      float* __restrict__ scores_out,
                                                      float* __restrict__ partials,
                                                      const float* __restrict__ lam_p,
                                                      const float* __restrict__ tau_p,
                                                      const float* __restrict__ temp_p) {
    __shared__ unsigned short As[2][2][4096];
    __shared__ unsigned short Bs[2][2][2048];
    __shared__ float rowpart[128];
    v4f acc[2][4];
    #pragma unroll
    for (int mt = 0; mt < 2; mt++)
        #pragma unroll
        for (int nt = 0; nt < 4; nt++) acc[mt][nt] = (v4f)(0.f);

    int mbase = blockIdx.y * 128, nbase = blockIdx.x * 64;
    gemm_mainloop(qwb, C_DIM, kb, C_DIM, mbase, nbase, C_DIM / 64, As, Bs, acc);

    int tid = threadIdx.x, wid = tid >> 6, lane = tid & 63;
    int quad = lane >> 4, l16 = lane & 15;

    float lam = lam_p[0], tau = tau_p[0], invT = 1.0f / temp_p[0];

    #pragma unroll
    for (int mt = 0; mt < 2; mt++)
        #pragma unroll
        for (int r = 0; r < 4; r++) {
            float rs = 0.f;
            int row = mbase + wid * 32 + mt * 16 + quad * 4 + r;
            #pragma unroll
            for (int nt = 0; nt < 4; nt++) {
                float s = acc[mt][nt][r];
                int col = nbase + nt * 16 + l16;
                scores_out[(size_t)row * N_DIM + col] = s;
                float g = 1.0f / (1.0f + __expf(-lam * (s - tau)));
                rs += g * __expf(s * invT);
            }
            rs += __shfl_xor(rs, 1, 64);
            rs += __shfl_xor(rs, 2, 64);
            rs += __shfl_xor(rs, 4, 64);
            rs += __shfl_xor(rs, 8, 64);
            if (l16 == 0)
                rowpart[wid * 32 + mt * 16 + quad * 4 + r] = rs;
        }
    __syncthreads();
    if (tid < 128)
        partials[(size_t)blockIdx.x * B_DIM + mbase + tid] = rowpart[tid];
}

// ---------------- alpha = g*exp(s/T) / rowsum (128 partials reduced in-kernel) ----------------
__global__ __launch_bounds__(256) void alpha_kernel(const float* __restrict__ scores,
                                                    const float* __restrict__ partials,
                                                    float* __restrict__ alpha,
                                                    const float* __restrict__ lam_p,
                                                    const float* __restrict__ tau_p,
                                                    const float* __restrict__ temp_p) {
    __shared__ float red[128];
    __shared__ float s_inv;
    int b = blockIdx.x;                       // one row per block, 512 blocks
    int tid = threadIdx.x;
    if (tid < 128) red[tid] = partials[(size_t)tid * B_DIM + b];
    __syncthreads();
    if (tid < 64) {
        float v = red[tid] + red[tid + 64];
        v += __shfl_xor(v, 1, 64);
        v += __shfl_xor(v, 2, 64);
        v += __shfl_xor(v, 4, 64);
        v += __shfl_xor(v, 8, 64);
        v += __shfl_xor(v, 16, 64);
        v += __shfl_xor(v, 32, 64);
        if (tid == 0) s_inv = 1.0f / (v + 1e-8f);
    }
    __syncthreads();
    float inv = s_inv;
    float lam = lam_p[0], tau = tau_p[0], invT = 1.0f / temp_p[0];
    const float4* srow = (const float4*)(scores + (size_t)b * N_DIM);
    float4* arow = (float4*)(alpha + (size_t)b * N_DIM);
    #pragma unroll
    for (int i = 0; i < 8; i++) {
        int idx = tid + i * 256;              // 0..2047 float4
        float4 s4 = srow[idx];
        float4 o;
        o.x = (1.0f / (1.0f + __expf(-lam * (s4.x - tau)))) * __expf(s4.x * invT) * inv;
        o.y = (1.0f / (1.0f + __expf(-lam * (s4.y - tau)))) * __expf(s4.y * invT) * inv;
        o.z = (1.0f / (1.0f + __expf(-lam * (s4.z - tau)))) * __expf(s4.z * invT) * inv;
        o.w = (1.0f / (1.0f + __expf(-lam * (s4.w - tau)))) * __expf(s4.w * invT) * inv;
        arow[idx] = o;
    }
}

extern "C" void kernel_launch(void* const* d_in, const int* in_sizes, int n_in,
                              void* d_out, int out_size, void* d_ws, size_t ws_size,
                              hipStream_t stream) {
    const float* z      = (const float*)d_in[0];
    const float* pool   = (const float*)d_in[1];
    const float* W_Q    = (const float*)d_in[2];
    const float* W_K    = (const float*)d_in[3];
    const float* logits = (const float*)d_in[4];
    const float* tau    = (const float*)d_in[5];
    const float* lam    = (const float*)d_in[6];
    const float* temp   = (const float*)d_in[7];

    float* alpha  = (float*)d_out;
    float* scores = alpha + (size_t)B_DIM * N_DIM;
    float* keys   = scores + (size_t)B_DIM * N_DIM;

    char* ws = (char*)d_ws;
    unsigned short* poolb = (unsigned short*)(ws);             // 16,777,216 B
    unsigned short* kb    = (unsigned short*)(ws + 16777216);  //  8,388,608 B
    unsigned short* wtb   = (unsigned short*)(ws + 25165824);  //  1,048,576 B
    unsigned short* wqt   = (unsigned short*)(ws + 26214400);  //    524,288 B
    unsigned short* zb    = (unsigned short*)(ws + 26738688);  //    524,288 B
    unsigned short* qwb   = (unsigned short*)(ws + 27262976);  //    524,288 B
    float* partials       = (float*)(ws + 27787264);           //    262,144 B (128 x 512)

    prep<<<dim3(4416), dim3(256), 0, stream>>>(pool, z, W_Q, W_K,
                                               poolb, zb, wqt, wtb);
    fused_gemms<<<dim3(544), dim3(256), 0, stream>>>(poolb, wtb, zb, wqt, logits,
                                                     keys, kb, qwb);
    scores_gemm<<<dim3(128, 4), dim3(256), 0, stream>>>(qwb, kb, scores, partials,
                                                        lam, tau, temp);
    alpha_kernel<<<dim3(512), dim3(256), 0, stream>>>(scores, partials, alpha,
                                                      lam, tau, temp);
}